// Round 13
// baseline (68.271 us; speedup 1.0000x reference)
//
#include <hip/hip_runtime.h>
#include <hip/hip_bf16.h>

typedef __bf16 bf16x8 __attribute__((ext_vector_type(8)));
typedef float f32x4 __attribute__((ext_vector_type(4)));

// Pre-kernel: clusters (128x512 f32) -> bf16 in ws, plus fp32 c2[128].
__global__ __launch_bounds__(64)
void prep_clusters(const float* __restrict__ c, __bf16* __restrict__ cb,
                   float* __restrict__ c2)
{
    const int row = blockIdx.x;     // 0..127
    const int l = threadIdx.x;      // 0..63
    const float* p = c + row * 512 + l * 8;
    f32x4 u0 = *(const f32x4*)p;
    f32x4 u1 = *(const f32x4*)(p + 4);
    bf16x8 v;
    float s = 0.f;
#pragma unroll
    for (int j = 0; j < 4; ++j) {
        v[j]     = (__bf16)u0[j];
        v[4 + j] = (__bf16)u1[j];
        s += u0[j] * u0[j] + u1[j] * u1[j];
    }
    *(bf16x8*)(cb + row * 512 + l * 8) = v;
#pragma unroll
    for (int off = 32; off >= 1; off >>= 1) s += __shfl_xor(s, off);
    if (l == 0) c2[row] = s;
}

// R11 (65.9 us) + LDS DOUBLE BUFFER for the x-tile -> ONE barrier per pass
// (was 2). With two 32 KB tile buffers the WAR barrier disappears: the single
// barrier serves {tile p+1 visible, rsx published}. rsx is parity-indexed per
// pass, closing the (previously latent) cross-pass rsx race exactly. LDS =
// 64 KB tiles + 8 KB qt + 0.5 KB rsx = 72.5 KB/block, still 2 blocks/CU.
// Everything else (persistent-B registers, full-line NT stores, reg-staged
// contiguous reads, vmcnt(2) counted wait) identical to R11.
__global__ __launch_bounds__(256, 2)
void cluster_q_mfma(const float* __restrict__ x,
                    const __bf16* __restrict__ cb,
                    const float* __restrict__ c2,
                    float* __restrict__ out)
{
    __shared__ float lds[2][16 * 512];   // 2 x 32 KB x-tiles (16 rows x 512)
    __shared__ float rsx[2][4][16];      // [pass parity][wave][row] partials
    __shared__ float qt[4][16 * 32];     // per-wave q bounce tile (2 KB)

    const int tid = threadIdx.x;
    const int l = tid & 63;
    const int w = tid >> 6;         // wave 0..3: owns cols w*32 .. w*32+31
    const int m = l & 15;           // fragment row (A) / col (B)
    const int g = l >> 4;           // k-group 0..3
    const long brow = (long)blockIdx.x * 256;

    float c2v[2];
#pragma unroll
    for (int nb = 0; nb < 2; ++nb) c2v[nb] = c2[w * 32 + nb * 16 + m];

    // Persistent B: cols w*32+nb*16+m, all 512 k. 32 x b128 loads, 128 VGPRs.
    bf16x8 bR[2][16];
#pragma unroll
    for (int nb = 0; nb < 2; ++nb)
#pragma unroll
        for (int ks = 0; ks < 16; ++ks)
            bR[nb][ks] = *(const bf16x8*)(
                cb + (w * 32 + nb * 16 + m) * 512 + ks * 32 + g * 8);

    // Staging geometry: instr i_ covers tile-row w*4+(i_>>1), half h=i_&1;
    // lane l takes chunk l of the 1KB half (fully linear global read).
    int cow[4];
#pragma unroll
    for (int q = 0; q < 4; ++q)
        cow[q] = (l & 56) + ((l & 7) ^ ((w * 4 + q) & 7));

    // LDS read bases (bytes): row m, chunk (ks*8 + (2g|2g+1)^(m&7)).
    const int rbo0 = m * 2048 + (((2 * g)     ^ (m & 7)) * 16);
    const int rbo1 = m * 2048 + (((2 * g + 1) ^ (m & 7)) * 16);

    // Output read-back geometry: 2 instructions of 8 rows x 8 chunks.
    const int orow_l = l >> 3;      // row within 8-row half
    const int opos = l & 7;         // 16B chunk position within 32-col piece

    f32x4 G[8];

#define SB __builtin_amdgcn_sched_barrier(0)
#define GLOAD(P)                                                          \
    { _Pragma("unroll")                                                   \
      for (int i_ = 0; i_ < 8; ++i_)                                      \
          G[i_] = *(const f32x4*)(x + (brow + (long)(P) * 16              \
                     + w * 4 + (i_ >> 1)) * 512 + (i_ & 1) * 256 + l * 4); }
#define DSWRITE(BUF)                                                      \
    { _Pragma("unroll")                                                   \
      for (int i_ = 0; i_ < 8; ++i_)                                      \
          *(f32x4*)(&lds[BUF][(w * 4 + (i_ >> 1)) * 512 + (i_ & 1) * 256  \
                         + cow[i_ >> 1] * 4]) = G[i_]; }

    // Prologue: tile 0 -> buf0; loads for tile 1 left in flight.
    GLOAD(0);
    asm volatile("s_waitcnt vmcnt(0)" ::: "memory");
    DSWRITE(0);
    GLOAD(1);
    asm volatile("s_waitcnt lgkmcnt(0)" ::: "memory");
    __builtin_amdgcn_s_barrier();

#pragma unroll 1
    for (int p = 0; p < 16; ++p) {
        const int cur = p & 1;
        const int par = p & 1;

        // P1: compute pass p from lds[cur].
        f32x4 acc[2] = {f32x4{0.f, 0.f, 0.f, 0.f}, f32x4{0.f, 0.f, 0.f, 0.f}};
        float x2p = 0.f;
        const char* L = (const char*)&lds[cur][0];
#pragma unroll
        for (int ks = 0; ks < 16; ++ks) {
            f32x4 u0 = *(const f32x4*)(L + rbo0 + ks * 128);
            f32x4 u1 = *(const f32x4*)(L + rbo1 + ks * 128);
            bf16x8 aF;
#pragma unroll
            for (int j = 0; j < 4; ++j) {
                aF[j]     = (__bf16)u0[j];
                aF[4 + j] = (__bf16)u1[j];
                x2p += u0[j] * u0[j] + u1[j] * u1[j];
            }
            acc[0] = __builtin_amdgcn_mfma_f32_16x16x32_bf16(aF, bR[0][ks], acc[0], 0, 0, 0);
            acc[1] = __builtin_amdgcn_mfma_f32_16x16x32_bf16(aF, bR[1][ks], acc[1], 0, 0, 0);
        }

        // P2: partial row sums into rsx[par][w].
        x2p += __shfl_xor(x2p, 16);
        x2p += __shfl_xor(x2p, 32);
        float x2r[4], rs[4];
#pragma unroll
        for (int r = 0; r < 4; ++r) {
            x2r[r] = __shfl(x2p, g * 4 + r);
            rs[r] = 0.f;
        }
#pragma unroll
        for (int nb = 0; nb < 2; ++nb)
#pragma unroll
            for (int r = 0; r < 4; ++r) {
                float d2 = fmaxf(x2r[r] + c2v[nb] - 2.f * acc[nb][r], 0.f);
                float qv = __builtin_amdgcn_rcpf(1.f + d2);  // ALPHA=1
                acc[nb][r] = qv;
                rs[r] += qv;
            }
#pragma unroll
        for (int r = 0; r < 4; ++r) {
            rs[r] += __shfl_xor(rs[r], 1);
            rs[r] += __shfl_xor(rs[r], 2);
            rs[r] += __shfl_xor(rs[r], 4);
            rs[r] += __shfl_xor(rs[r], 8);
        }
        if (m == 0) {
#pragma unroll
            for (int r = 0; r < 4; ++r) rsx[par][w][g * 4 + r] = rs[r];
        }
        SB;

        // P3: staging into the OTHER buffer — no WAR barrier needed (dbuf).
        // vmcnt: outstanding = 8 loads(p+1) [oldest] + 2 NT stores(p-1)
        // [newest] -> vmcnt(2); at p==0 there are no stores yet -> vmcnt(0).
        if (p < 15) {
            if (p == 0) { asm volatile("s_waitcnt vmcnt(0)" ::: "memory"); }
            else        { asm volatile("s_waitcnt vmcnt(2)" ::: "memory"); }
            SB;
            DSWRITE(cur ^ 1);
            if (p < 14) { GLOAD(p + 2); }   // G free again after DSWRITE
        }

        // SINGLE barrier: tile p+1 visible AND rsx[par] published.
        asm volatile("s_waitcnt lgkmcnt(0)" ::: "memory");
        __builtin_amdgcn_s_barrier();
        SB;

        // P4: epilogue — inv from rsx[par], normalize, qt bounce, 2 full-line
        // NT stores. Next rsx write targets parity^1 -> race-free.
        float inv[4];
#pragma unroll
        for (int r = 0; r < 4; ++r) {
            const int row16 = g * 4 + r;
            inv[r] = __builtin_amdgcn_rcpf(
                rsx[par][0][row16] + rsx[par][1][row16] +
                rsx[par][2][row16] + rsx[par][3][row16]);
        }
#pragma unroll
        for (int r = 0; r < 4; ++r) {
            const int row16 = g * 4 + r;
#pragma unroll
            for (int nb = 0; nb < 2; ++nb) {
                const int chunk = nb * 4 + (m >> 2);
                qt[w][row16 * 32 + ((chunk ^ (row16 & 7)) * 4) + (m & 3)] =
                    acc[nb][r] * inv[r];
            }
        }
        // wave-private RAW on qt: compiler inserts the needed lgkmcnt.
        const long obase = brow + p * 16;
#pragma unroll
        for (int h = 0; h < 2; ++h) {
            const int row16 = h * 8 + orow_l;
            f32x4 v = *(const f32x4*)&qt[w][row16 * 32 +
                                            ((opos ^ (row16 & 7)) * 4)];
            __builtin_nontemporal_store(
                v, (f32x4*)(out + (obase + row16) * 128 + w * 32 + opos * 4));
        }
        SB;
    }
#undef GLOAD
#undef DSWRITE
#undef SB
}

extern "C" void kernel_launch(void* const* d_in, const int* in_sizes, int n_in,
                              void* d_out, int out_size, void* d_ws, size_t ws_size,
                              hipStream_t stream)
{
    const float* x = (const float*)d_in[0];
    const float* c = (const float*)d_in[1];
    float* out = (float*)d_out;

    float*  c2ws = (float*)d_ws;                        // 128 floats
    __bf16* cbws = (__bf16*)((char*)d_ws + 1024);       // 128x512 bf16 = 128 KB

    hipLaunchKernelGGL(prep_clusters, dim3(128), dim3(64), 0, stream, c, cbws, c2ws);

    const int N = in_sizes[0] / 512;                    // 131072 rows
    dim3 grid(N / 256), block(256);                     // 512 blocks = 2/CU
    hipLaunchKernelGGL(cluster_q_mfma, grid, block, 0, stream, x, cbws, c2ws, out);
}